// Round 1
// baseline (895.897 us; speedup 1.0000x reference)
//
#include <hip/hip_runtime.h>

// MPNN: N=50000, E=800000, DIN=64, EIN=32, EOUT=64, H=128, DOUT=64
// R1: latency-bound edge_kernel (Occ 23%, all pipes <15%).
//  - LDS union (eins/hsm/outs share one 33.8KB buffer) -> 4 blocks/CU (was 2)
//  - nf pre-converted to bf16 once (lives in d_out uh_n region until agg overwrites)
//  - soft_kernel chain walks eliminated: exp+atomicAdd(den) fused into edge epilogue
//    (logits ~N(0,0.5); max-subtraction unnecessary in f32, clamp +-50 for safety)

typedef unsigned short u16;
typedef __attribute__((ext_vector_type(8))) short bf16x8;
typedef __attribute__((ext_vector_type(4))) float f32x4;

#define NN 50000
#define NE 800000

__device__ __forceinline__ u16 f2bf(float f){
  union { float f; unsigned int i; } v; v.f = f;
  unsigned int i = v.i;
  return (u16)((i + 0x7FFFu + ((i >> 16) & 1u)) >> 16);  // RNE
}
__device__ __forceinline__ uint2 f4tobf(float4 f){
  uint2 p;
  p.x = (unsigned)f2bf(f.x) | ((unsigned)f2bf(f.y) << 16);
  p.y = (unsigned)f2bf(f.z) | ((unsigned)f2bf(f.w) << 16);
  return p;
}

// ---------------- prep: f32 weights -> transposed bf16 [n][k]; head=-1; den=0 ----------
__global__ void prep_kernel(const float* __restrict__ We1, const float* __restrict__ Wa1,
                            const float* __restrict__ We2, const float* __restrict__ Wa2,
                            const float* __restrict__ Wn1, const float* __restrict__ Wn2,
                            u16* __restrict__ w1t, u16* __restrict__ w2t,
                            u16* __restrict__ wn1t, u16* __restrict__ wn2t,
                            int* __restrict__ head, float* __restrict__ den)
{
  int i = blockIdx.x * 256 + threadIdx.x;
  if (i < 40960) {
    int n = i / 160, k = i % 160;
    w1t[i] = f2bf((n < 128) ? We1[k*128 + n] : Wa1[k*128 + (n-128)]);
  } else if (i < 51200) {
    int j = i - 40960; int n = j / 128, k = j % 128;
    float v = (n < 64) ? We2[k*64 + n] : ((n == 64) ? Wa2[k] : 0.f);
    w2t[j] = f2bf(v);
  } else if (i < 67584) {
    int j = i - 51200; int n = j / 128, k = j % 128;
    wn1t[j] = f2bf(Wn1[k*128 + n]);
  } else if (i < 75776) {
    int j = i - 67584; int n = j / 128, k = j % 128;
    wn2t[j] = f2bf(Wn2[k*64 + n]);
  } else if (i < 125776) {
    head[i - 75776] = -1;
  } else if (i < 175776) {
    den[i - 125776] = 0.f;
  }
}

// ---------------- nf f32 -> bf16 (once; removes convert from edge gather path) --------
__global__ void nfbf_kernel(const float* __restrict__ nf, u16* __restrict__ nfb)
{
  int i = blockIdx.x * 256 + threadIdx.x;   // 800000 = NN*16 float4 chunks
  if (i >= NN * 16) return;
  float4 f = *(const float4*)(nf + (size_t)i * 4);
  *(uint2*)&nfb[(size_t)i * 4] = f4tobf(f);
}

// ---------------- linked-list build over dst ----------------
__global__ void link_kernel(const int* __restrict__ dst, int* __restrict__ head,
                            int* __restrict__ nxt)
{
  int e = blockIdx.x * 256 + threadIdx.x;
  if (e >= NE) return;
  nxt[e] = atomicExch(&head[dst[e]], e);
}

// ---------------- edge MLP + attn logit + fused exp/den (MFMA) ----------------
// LDS union: eins[64][168] u16 (21.5KB) / hsm 4x[16][264] u16 (33.8KB) / outs[64][64] f32
// (16.4KB) share one 33792B buffer -> 34.3KB/block -> 4 blocks/CU.
__global__ __launch_bounds__(256, 4) void edge_kernel(
    const u16* __restrict__ nfb, const float* __restrict__ ef,
    const int* __restrict__ src, const int* __restrict__ dst,
    const u16* __restrict__ w1t, const u16* __restrict__ w2t,
    const float* __restrict__ be1, const float* __restrict__ ba1,
    const float* __restrict__ be2, const float* __restrict__ ba2,
    float* __restrict__ uh_e, float* __restrict__ logits,
    float* __restrict__ den)
{
  __shared__ u16 smem[16896];        // 33792 B union
  __shared__ int s_src[64], s_dst[64];
  u16* eins = smem;                  // [64][168] (160 + 8 pad)
  float* outs = (float*)smem;        // [64][64]

  const int t = threadIdx.x;
  const int base = blockIdx.x * 64;

  if (t < 64)        s_src[t]      = src[base + t];
  else if (t < 128)  s_dst[t - 64] = dst[base + (t - 64)];
  __syncthreads();

  // gather bf16 rows: 64 bf16/row = 16 lanes x uint2 (128 B/row, no convert)
  #pragma unroll
  for (int i = 0; i < 4; i++) {
    int idx = i*256 + t;
    int e = idx >> 4, c = idx & 15;
    uint2 v = *(const uint2*)(nfb + (size_t)s_src[e]*64 + c*4);
    *(uint2*)&eins[e*168 + c*4] = v;
  }
  #pragma unroll
  for (int i = 0; i < 4; i++) {
    int idx = i*256 + t;
    int e = idx >> 4, c = idx & 15;
    uint2 v = *(const uint2*)(nfb + (size_t)s_dst[e]*64 + c*4);
    *(uint2*)&eins[e*168 + 64 + c*4] = v;
  }
  #pragma unroll
  for (int i = 0; i < 2; i++) {
    int idx = i*256 + t;
    int e = idx >> 3, c = idx & 7;
    float4 f = *(const float4*)(ef + (size_t)(base + e)*32 + c*4);
    *(uint2*)&eins[e*168 + 128 + c*4] = f4tobf(f);
  }
  __syncthreads();

  const int lane = t & 63, wave = t >> 6;
  const int r = lane & 15, quad = lane >> 4;

  // ---- layer 1: [64x160] @ [160x256] (We1|Wa1 fused) ----
  f32x4 acc[16];
  #pragma unroll
  for (int i = 0; i < 16; i++) acc[i] = {0.f, 0.f, 0.f, 0.f};

  const u16* arow = &eins[(wave*16 + r)*168 + quad*8];
  #pragma unroll
  for (int k0 = 0; k0 < 160; k0 += 32) {
    bf16x8 a = *(const bf16x8*)(arow + k0);
    #pragma unroll
    for (int tt = 0; tt < 16; tt++) {
      bf16x8 b = *(const bf16x8*)(w1t + (size_t)(tt*16 + r)*160 + k0 + quad*8);
      acc[tt] = __builtin_amdgcn_mfma_f32_16x16x32_bf16(a, b, acc[tt], 0, 0, 0);
    }
  }
  __syncthreads();   // all eins reads done before hsm (aliased) is written

  // bias + relu, C-layout (col=lane&15, row=quad*4+i) -> LDS row-major
  u16* hb = smem + wave*(16*264);    // hsm[wave]: [16][264] (256 + 8 pad)
  #pragma unroll
  for (int tt = 0; tt < 16; tt++) {
    int col = tt*16 + r;
    float bias = (col < 128) ? be1[col] : ba1[col - 128];
    #pragma unroll
    for (int i = 0; i < 4; i++) {
      float h = fmaxf(acc[tt][i] + bias, 0.f);
      hb[(quad*4 + i)*264 + col] = f2bf(h);
    }
  }
  __syncthreads();

  // ---- layer 2: uh_e = h_e[16x128] @ We2[128x64]; logit = h_a @ Wa2 ----
  f32x4 acc2[5];
  #pragma unroll
  for (int i = 0; i < 5; i++) acc2[i] = {0.f, 0.f, 0.f, 0.f};
  #pragma unroll
  for (int k0 = 0; k0 < 128; k0 += 32) {
    bf16x8 ae = *(const bf16x8*)&hb[r*264 + k0 + quad*8];
    bf16x8 aa = *(const bf16x8*)&hb[r*264 + 128 + k0 + quad*8];
    #pragma unroll
    for (int tt = 0; tt < 4; tt++) {
      bf16x8 b = *(const bf16x8*)(w2t + (size_t)(tt*16 + r)*128 + k0 + quad*8);
      acc2[tt] = __builtin_amdgcn_mfma_f32_16x16x32_bf16(ae, b, acc2[tt], 0, 0, 0);
    }
    bf16x8 b4 = *(const bf16x8*)(w2t + (size_t)(64 + r)*128 + k0 + quad*8);
    acc2[4] = __builtin_amdgcn_mfma_f32_16x16x32_bf16(aa, b4, acc2[4], 0, 0, 0);
  }
  __syncthreads();   // all hsm reads done before outs (aliased) is written

  // epilogue: uh_e (f32) -> LDS staging; exp(logit) -> global + atomicAdd den[dst]
  #pragma unroll
  for (int tt = 0; tt < 4; tt++) {
    int col = tt*16 + r;
    float bias = be2[col];
    #pragma unroll
    for (int i = 0; i < 4; i++)
      outs[(wave*16 + quad*4 + i)*64 + col] = acc2[tt][i] + bias;
  }
  if (r == 0) {
    float bias = ba2[0];
    #pragma unroll
    for (int i = 0; i < 4; i++) {
      int row = wave*16 + quad*4 + i;
      float x = __expf(fminf(fmaxf(acc2[4][i] + bias, -50.f), 50.f));
      logits[base + row] = x;                 // logits buffer now holds exp() values
      atomicAdd(&den[s_dst[row]], x);
    }
  }
  __syncthreads();

  // coalesced f32 uh_e store: 64 rows x 16 float4
  #pragma unroll
  for (int i = 0; i < 4; i++) {
    int idx = i*256 + t;
    int row = idx >> 4, c = idx & 15;
    *(float4*)(uh_e + (size_t)(base + row)*64 + c*4) = *(const float4*)&outs[row*64 + c*4];
  }
}

// ---------------- attention-weighted aggregation (wave per node) ----------------
// writes f32 agg into d_out's uh_n region (node_kernel stages it before overwriting)
__global__ void agg_kernel(const int* __restrict__ head, const int* __restrict__ nxt,
                           const float* __restrict__ attn_u, const float* __restrict__ den,
                           const float* __restrict__ uh_e, float* __restrict__ aggf)
{
  int gid = blockIdx.x * 256 + threadIdx.x;
  int v = gid >> 6, lane = gid & 63;
  if (v >= NN) return;
  float inv = 1.f / fmaxf(den[v], 1e-38f);
  float acc = 0.f;
  int e = head[v];
  while (e >= 0) {
    acc += (attn_u[e] * inv) * uh_e[(size_t)e*64 + lane];
    e = nxt[e];
  }
  aggf[(size_t)v*64 + lane] = acc;
}

// ---------------- node MLP (MFMA); reads agg from uh_n region, overwrites with uh_n ----
// LDS union: xs[64][136] / hsm 4x[16][136] / outs[64][64] -> 17.4KB/block
__global__ __launch_bounds__(256, 4) void node_kernel(
    const float* __restrict__ aggf, const float* __restrict__ nf,
    const u16* __restrict__ wn1t, const u16* __restrict__ wn2t,
    const float* __restrict__ bn1, const float* __restrict__ bn2,
    float* __restrict__ uh_n)
{
  __shared__ u16 smem[8704];         // 17408 B union
  u16* xs = smem;                    // [64][136] (128 + 8 pad)
  float* outs = (float*)smem;        // [64][64]

  const int t = threadIdx.x;
  const int base = blockIdx.x * 64;

  // xs: cols 0..63 = aggf (f32->bf16), cols 64..127 = nf (f32->bf16); 32 float4/row
  #pragma unroll
  for (int i = 0; i < 8; i++) {
    int idx = i*256 + t;            // 0..2047
    int row = idx >> 5, c = idx & 31;
    int v = base + row;
    float4 f = {0.f, 0.f, 0.f, 0.f};
    if (v < NN) {
      if (c < 16) f = *(const float4*)(aggf + (size_t)v*64 + c*4);
      else        f = *(const float4*)(nf   + (size_t)v*64 + (c-16)*4);
    }
    *(uint2*)&xs[row*136 + c*4] = f4tobf(f);
  }
  __syncthreads();

  const int lane = t & 63, wave = t >> 6;
  const int r = lane & 15, quad = lane >> 4;

  f32x4 acc1[8];
  #pragma unroll
  for (int i = 0; i < 8; i++) acc1[i] = {0.f, 0.f, 0.f, 0.f};
  #pragma unroll
  for (int k0 = 0; k0 < 128; k0 += 32) {
    bf16x8 a = *(const bf16x8*)&xs[(wave*16 + r)*136 + k0 + quad*8];
    #pragma unroll
    for (int tt = 0; tt < 8; tt++) {
      bf16x8 b = *(const bf16x8*)(wn1t + (size_t)(tt*16 + r)*128 + k0 + quad*8);
      acc1[tt] = __builtin_amdgcn_mfma_f32_16x16x32_bf16(a, b, acc1[tt], 0, 0, 0);
    }
  }
  __syncthreads();   // all xs reads done before hsm (aliased) is written

  u16* hb = smem + wave*(16*136);    // hsm[wave]: [16][136]
  #pragma unroll
  for (int tt = 0; tt < 8; tt++) {
    int col = tt*16 + r;
    float bias = bn1[col];
    #pragma unroll
    for (int i = 0; i < 4; i++) {
      float h = fmaxf(acc1[tt][i] + bias, 0.f);
      hb[(quad*4 + i)*136 + col] = f2bf(h);
    }
  }
  __syncthreads();

  f32x4 acc2[4];
  #pragma unroll
  for (int i = 0; i < 4; i++) acc2[i] = {0.f, 0.f, 0.f, 0.f};
  #pragma unroll
  for (int k0 = 0; k0 < 128; k0 += 32) {
    bf16x8 a = *(const bf16x8*)&hb[r*136 + k0 + quad*8];
    #pragma unroll
    for (int tt = 0; tt < 4; tt++) {
      bf16x8 b = *(const bf16x8*)(wn2t + (size_t)(tt*16 + r)*128 + k0 + quad*8);
      acc2[tt] = __builtin_amdgcn_mfma_f32_16x16x32_bf16(a, b, acc2[tt], 0, 0, 0);
    }
  }
  __syncthreads();   // all hsm reads done before outs (aliased) is written

  #pragma unroll
  for (int tt = 0; tt < 4; tt++) {
    int col = tt*16 + r;
    float bias = bn2[col];
    #pragma unroll
    for (int i = 0; i < 4; i++)
      outs[(wave*16 + quad*4 + i)*64 + col] = acc2[tt][i] + bias;
  }
  __syncthreads();

  #pragma unroll
  for (int i = 0; i < 4; i++) {
    int idx = i*256 + t;
    int row = idx >> 4, c = idx & 15;
    int v2 = base + row;
    if (v2 < NN)
      *(float4*)(uh_n + (size_t)v2*64 + c*4) = *(const float4*)&outs[row*64 + c*4];
  }
}

// ---------------- launch ----------------
extern "C" void kernel_launch(void* const* d_in, const int* in_sizes, int n_in,
                              void* d_out, int out_size, void* d_ws, size_t ws_size,
                              hipStream_t stream)
{
  const float* nf  = (const float*)d_in[0];
  const float* ef  = (const float*)d_in[1];
  const int*   src = (const int*)d_in[2];
  const int*   dst = (const int*)d_in[3];
  const float* We1 = (const float*)d_in[4];
  const float* be1 = (const float*)d_in[5];
  const float* We2 = (const float*)d_in[6];
  const float* be2 = (const float*)d_in[7];
  const float* Wa1 = (const float*)d_in[8];
  const float* ba1 = (const float*)d_in[9];
  const float* Wa2 = (const float*)d_in[10];
  const float* ba2 = (const float*)d_in[11];
  const float* Wn1 = (const float*)d_in[12];
  const float* bn1 = (const float*)d_in[13];
  const float* Wn2 = (const float*)d_in[14];
  const float* bn2 = (const float*)d_in[15];

  // workspace layout (bytes), total 6,951,552 B (~6.6 MiB)
  char* ws = (char*)d_ws;
  u16*   w1t    = (u16*)  (ws + 0);         //  81920 B
  u16*   w2t    = (u16*)  (ws + 81920);     //  20480 B
  u16*   wn1t   = (u16*)  (ws + 102400);    //  32768 B
  u16*   wn2t   = (u16*)  (ws + 135168);    //  16384 B
  float* logits = (float*)(ws + 151552);    //  NE*4 (holds exp() after edge_kernel)
  float* den    = (float*)(ws + 3351552);   //  NN*4 (atomicAdd target, zeroed by prep)
  int*   head   = (int*)  (ws + 3551552);   //  NN*4
  int*   nxt    = (int*)  (ws + 3751552);   //  NE*4  -> end 6,951,552

  float* uh_n = (float*)d_out;                     // [NN, 64] f32
  float* uh_e = (float*)d_out + (size_t)NN * 64;   // [NE, 64] f32
  // nfb (bf16 nf, 6.4 MB) lives in the uh_n region: consumed only by edge_kernel,
  // which completes before agg_kernel overwrites the region with aggf.
  u16*   nfb  = (u16*)d_out;
  float* aggf = uh_n;

  prep_kernel<<<687, 256, 0, stream>>>(We1, Wa1, We2, Wa2, Wn1, Wn2,
                                       w1t, w2t, wn1t, wn2t, head, den);
  nfbf_kernel<<<3125, 256, 0, stream>>>(nf, nfb);
  link_kernel<<<(NE + 255)/256, 256, 0, stream>>>(dst, head, nxt);
  edge_kernel<<<NE/64, 256, 0, stream>>>(nfb, ef, src, dst, w1t, w2t,
                                         be1, ba1, be2, ba2, uh_e, logits, den);
  agg_kernel<<<(NN*64)/256, 256, 0, stream>>>(head, nxt, logits, den, uh_e, aggf);
  node_kernel<<<(NN + 63)/64, 256, 0, stream>>>(aggf, nf, wn1t, wn2t, bn1, bn2, uh_n);
}

// Round 2
// 649.651 us; speedup vs baseline: 1.3790x; 1.3790x over previous
//
#include <hip/hip_runtime.h>

// MPNN: N=50000, E=800000, DIN=64, EIN=32, EOUT=64, H=128, DOUT=64
// R2: R1 showed occupancy-doubling changed nothing -> bottleneck = per-CU L2 weight
// streaming (row-split waves each re-read all 100KB weights per block = 400KB/block).
//  - edge_kernel waves now COLUMN-split: each wave reads only its 64-col weight slice
//    (112KB/block total, 3.6x less L2 traffic; serialized-per-CU cost 145us -> ~40us)
//  - atomics/den removed: agg divides by sum-of-exp it accumulates during its own walk
//    (agg = (sum ex*uh)/(sum ex)); edge epilogue just stores exp(logit)

typedef unsigned short u16;
typedef __attribute__((ext_vector_type(8))) short bf16x8;
typedef __attribute__((ext_vector_type(4))) float f32x4;

#define NN 50000
#define NE 800000

__device__ __forceinline__ u16 f2bf(float f){
  union { float f; unsigned int i; } v; v.f = f;
  unsigned int i = v.i;
  return (u16)((i + 0x7FFFu + ((i >> 16) & 1u)) >> 16);  // RNE
}
__device__ __forceinline__ uint2 f4tobf(float4 f){
  uint2 p;
  p.x = (unsigned)f2bf(f.x) | ((unsigned)f2bf(f.y) << 16);
  p.y = (unsigned)f2bf(f.z) | ((unsigned)f2bf(f.w) << 16);
  return p;
}

// ---------------- prep: f32 weights -> transposed bf16 [n][k]; head = -1 ----------------
__global__ void prep_kernel(const float* __restrict__ We1, const float* __restrict__ Wa1,
                            const float* __restrict__ We2, const float* __restrict__ Wa2,
                            const float* __restrict__ Wn1, const float* __restrict__ Wn2,
                            u16* __restrict__ w1t, u16* __restrict__ w2t,
                            u16* __restrict__ wn1t, u16* __restrict__ wn2t,
                            int* __restrict__ head)
{
  int i = blockIdx.x * 256 + threadIdx.x;
  if (i < 40960) {
    int n = i / 160, k = i % 160;
    w1t[i] = f2bf((n < 128) ? We1[k*128 + n] : Wa1[k*128 + (n-128)]);
  } else if (i < 51200) {
    int j = i - 40960; int n = j / 128, k = j % 128;
    float v = (n < 64) ? We2[k*64 + n] : ((n == 64) ? Wa2[k] : 0.f);
    w2t[j] = f2bf(v);
  } else if (i < 67584) {
    int j = i - 51200; int n = j / 128, k = j % 128;
    wn1t[j] = f2bf(Wn1[k*128 + n]);
  } else if (i < 75776) {
    int j = i - 67584; int n = j / 128, k = j % 128;
    wn2t[j] = f2bf(Wn2[k*64 + n]);
  } else if (i < 125776) {
    head[i - 75776] = -1;
  }
}

// ---------------- nf f32 -> bf16 (once) ----------------
__global__ void nfbf_kernel(const float* __restrict__ nf, u16* __restrict__ nfb)
{
  int i = blockIdx.x * 256 + threadIdx.x;   // NN*16 float4 chunks
  if (i >= NN * 16) return;
  float4 f = *(const float4*)(nf + (size_t)i * 4);
  *(uint2*)&nfb[(size_t)i * 4] = f4tobf(f);
}

// ---------------- linked-list build over dst ----------------
__global__ void link_kernel(const int* __restrict__ dst, int* __restrict__ head,
                            int* __restrict__ nxt)
{
  int e = blockIdx.x * 256 + threadIdx.x;
  if (e >= NE) return;
  nxt[e] = atomicExch(&head[dst[e]], e);
}

// ---------------- edge MLP + attn logit (MFMA, column-split waves) ----------------
// LDS union: eins[64][168] u16 (21.5KB) / hsm [64][264] u16 (33.8KB) / outs[64][64] f32.
// Wave w owns L1 output cols [64w,64w+64) and L2 colfrag w (+ logit rowfrag w):
// per-wave weight slice = 28KB vs 100KB row-split.
__global__ __launch_bounds__(256, 4) void edge_kernel(
    const u16* __restrict__ nfb, const float* __restrict__ ef,
    const int* __restrict__ src, const int* __restrict__ dst,
    const u16* __restrict__ w1t, const u16* __restrict__ w2t,
    const float* __restrict__ be1, const float* __restrict__ ba1,
    const float* __restrict__ be2, const float* __restrict__ ba2,
    float* __restrict__ uh_e, float* __restrict__ exu)
{
  __shared__ u16 smem[16896];        // 33792 B union
  __shared__ int s_src[64], s_dst[64];
  u16* eins = smem;                  // [64][168] (160 + 8 pad)
  u16* hsm  = smem;                  // [64][264] (256 + 8 pad)
  float* outs = (float*)smem;        // [64][64]

  const int t = threadIdx.x;
  const int base = blockIdx.x * 64;

  if (t < 64)        s_src[t]      = src[base + t];
  else if (t < 128)  s_dst[t - 64] = dst[base + (t - 64)];
  __syncthreads();

  // gather bf16 rows: 64 bf16/row = 16 lanes x uint2 (128 B/row)
  #pragma unroll
  for (int i = 0; i < 4; i++) {
    int idx = i*256 + t;
    int e = idx >> 4, c = idx & 15;
    uint2 v = *(const uint2*)(nfb + (size_t)s_src[e]*64 + c*4);
    *(uint2*)&eins[e*168 + c*4] = v;
  }
  #pragma unroll
  for (int i = 0; i < 4; i++) {
    int idx = i*256 + t;
    int e = idx >> 4, c = idx & 15;
    uint2 v = *(const uint2*)(nfb + (size_t)s_dst[e]*64 + c*4);
    *(uint2*)&eins[e*168 + 64 + c*4] = v;
  }
  #pragma unroll
  for (int i = 0; i < 2; i++) {
    int idx = i*256 + t;
    int e = idx >> 3, c = idx & 7;
    float4 f = *(const float4*)(ef + (size_t)(base + e)*32 + c*4);
    *(uint2*)&eins[e*168 + 128 + c*4] = f4tobf(f);
  }
  __syncthreads();

  const int lane = t & 63, wave = t >> 6;
  const int r = lane & 15, quad = lane >> 4;

  // ---- layer 1: [64x160] @ [160x256]; wave w -> colfrags w*4..w*4+3 ----
  f32x4 acc[4][4];                   // [rowfrag][colfrag_local]
  #pragma unroll
  for (int rf = 0; rf < 4; rf++)
    #pragma unroll
    for (int j = 0; j < 4; j++) acc[rf][j] = {0.f, 0.f, 0.f, 0.f};

  #pragma unroll
  for (int k0 = 0; k0 < 160; k0 += 32) {
    bf16x8 a[4];
    #pragma unroll
    for (int rf = 0; rf < 4; rf++)
      a[rf] = *(const bf16x8*)&eins[(rf*16 + r)*168 + k0 + quad*8];
    #pragma unroll
    for (int j = 0; j < 4; j++) {
      bf16x8 b = *(const bf16x8*)(w1t + (size_t)((wave*4 + j)*16 + r)*160 + k0 + quad*8);
      #pragma unroll
      for (int rf = 0; rf < 4; rf++)
        acc[rf][j] = __builtin_amdgcn_mfma_f32_16x16x32_bf16(a[rf], b, acc[rf][j], 0, 0, 0);
    }
  }
  __syncthreads();   // all eins reads done before hsm (aliased) is written

  // bias + relu -> hsm[row][col]; wave w writes cols [64w,64w+64), all 64 rows
  #pragma unroll
  for (int j = 0; j < 4; j++) {
    int col = (wave*4 + j)*16 + r;
    float bias = (wave < 2) ? be1[col] : ba1[col - 128];
    #pragma unroll
    for (int rf = 0; rf < 4; rf++)
      #pragma unroll
      for (int i = 0; i < 4; i++) {
        float h = fmaxf(acc[rf][j][i] + bias, 0.f);
        hsm[(rf*16 + quad*4 + i)*264 + col] = f2bf(h);
      }
  }
  __syncthreads();

  // ---- layer 2: uh_e cols w*16+r (colfrag w); logit rowfrag w ----
  f32x4 acc2[4];                     // [rowfrag]
  f32x4 accl = {0.f, 0.f, 0.f, 0.f};
  #pragma unroll
  for (int rf = 0; rf < 4; rf++) acc2[rf] = {0.f, 0.f, 0.f, 0.f};

  #pragma unroll
  for (int k0 = 0; k0 < 128; k0 += 32) {
    bf16x8 bw = *(const bf16x8*)(w2t + (size_t)(wave*16 + r)*128 + k0 + quad*8);
    #pragma unroll
    for (int rf = 0; rf < 4; rf++) {
      bf16x8 ae = *(const bf16x8*)&hsm[(rf*16 + r)*264 + k0 + quad*8];
      acc2[rf] = __builtin_amdgcn_mfma_f32_16x16x32_bf16(ae, bw, acc2[rf], 0, 0, 0);
    }
    bf16x8 al = *(const bf16x8*)&hsm[(wave*16 + r)*264 + 128 + k0 + quad*8];
    bf16x8 bl = *(const bf16x8*)(w2t + (size_t)(64 + r)*128 + k0 + quad*8);
    accl = __builtin_amdgcn_mfma_f32_16x16x32_bf16(al, bl, accl, 0, 0, 0);
  }
  __syncthreads();   // all hsm reads done before outs (aliased) is written

  // epilogue: uh_e (f32) -> LDS staging; exp(logit) -> global
  {
    int col = wave*16 + r;
    float bias = be2[col];
    #pragma unroll
    for (int rf = 0; rf < 4; rf++)
      #pragma unroll
      for (int i = 0; i < 4; i++)
        outs[(rf*16 + quad*4 + i)*64 + col] = acc2[rf][i] + bias;
  }
  if (r == 0) {
    float bias = ba2[0];
    #pragma unroll
    for (int i = 0; i < 4; i++) {
      int row = wave*16 + quad*4 + i;
      float x = __expf(fminf(fmaxf(accl[i] + bias, -50.f), 50.f));
      exu[base + row] = x;           // unnormalized exp(logit)
    }
  }
  __syncthreads();

  // coalesced f32 uh_e store: 64 rows x 16 float4
  #pragma unroll
  for (int i = 0; i < 4; i++) {
    int idx = i*256 + t;
    int row = idx >> 4, c = idx & 15;
    *(float4*)(uh_e + (size_t)(base + row)*64 + c*4) = *(const float4*)&outs[row*64 + c*4];
  }
}

// ---------------- attention-weighted aggregation (wave per node) ----------------
// denominator folded in: agg = (sum ex*uh) / (sum ex); writes f32 agg into d_out uh_n region
__global__ void agg_kernel(const int* __restrict__ head, const int* __restrict__ nxt,
                           const float* __restrict__ exu,
                           const float* __restrict__ uh_e, float* __restrict__ aggf)
{
  int gid = blockIdx.x * 256 + threadIdx.x;
  int v = gid >> 6, lane = gid & 63;
  if (v >= NN) return;
  float acc = 0.f, s = 0.f;
  int e = head[v];
  while (e >= 0) {
    float x = exu[e];                // broadcast load (all lanes same addr)
    s += x;
    acc += x * uh_e[(size_t)e*64 + lane];
    e = nxt[e];
  }
  aggf[(size_t)v*64 + lane] = acc / fmaxf(s, 1e-38f);
}

// ---------------- node MLP (MFMA); reads agg from uh_n region, overwrites with uh_n ----
// LDS union: xs[64][136] / hsm 4x[16][136] / outs[64][64] -> 17.4KB/block
__global__ __launch_bounds__(256, 4) void node_kernel(
    const float* __restrict__ aggf, const float* __restrict__ nf,
    const u16* __restrict__ wn1t, const u16* __restrict__ wn2t,
    const float* __restrict__ bn1, const float* __restrict__ bn2,
    float* __restrict__ uh_n)
{
  __shared__ u16 smem[8704];         // 17408 B union
  u16* xs = smem;                    // [64][136] (128 + 8 pad)
  float* outs = (float*)smem;        // [64][64]

  const int t = threadIdx.x;
  const int base = blockIdx.x * 64;

  // xs: cols 0..63 = aggf (f32->bf16), cols 64..127 = nf (f32->bf16); 32 float4/row
  #pragma unroll
  for (int i = 0; i < 8; i++) {
    int idx = i*256 + t;            // 0..2047
    int row = idx >> 5, c = idx & 31;
    int v = base + row;
    float4 f = {0.f, 0.f, 0.f, 0.f};
    if (v < NN) {
      if (c < 16) f = *(const float4*)(aggf + (size_t)v*64 + c*4);
      else        f = *(const float4*)(nf   + (size_t)v*64 + (c-16)*4);
    }
    *(uint2*)&xs[row*136 + c*4] = f4tobf(f);
  }
  __syncthreads();

  const int lane = t & 63, wave = t >> 6;
  const int r = lane & 15, quad = lane >> 4;

  f32x4 acc1[8];
  #pragma unroll
  for (int i = 0; i < 8; i++) acc1[i] = {0.f, 0.f, 0.f, 0.f};
  #pragma unroll
  for (int k0 = 0; k0 < 128; k0 += 32) {
    bf16x8 a = *(const bf16x8*)&xs[(wave*16 + r)*136 + k0 + quad*8];
    #pragma unroll
    for (int tt = 0; tt < 8; tt++) {
      bf16x8 b = *(const bf16x8*)(wn1t + (size_t)(tt*16 + r)*128 + k0 + quad*8);
      acc1[tt] = __builtin_amdgcn_mfma_f32_16x16x32_bf16(a, b, acc1[tt], 0, 0, 0);
    }
  }
  __syncthreads();   // all xs reads done before hsm (aliased) is written

  u16* hb = smem + wave*(16*136);    // hsm[wave]: [16][136]
  #pragma unroll
  for (int tt = 0; tt < 8; tt++) {
    int col = tt*16 + r;
    float bias = bn1[col];
    #pragma unroll
    for (int i = 0; i < 4; i++) {
      float h = fmaxf(acc1[tt][i] + bias, 0.f);
      hb[(quad*4 + i)*136 + col] = f2bf(h);
    }
  }
  __syncthreads();

  f32x4 acc2[4];
  #pragma unroll
  for (int i = 0; i < 4; i++) acc2[i] = {0.f, 0.f, 0.f, 0.f};
  #pragma unroll
  for (int k0 = 0; k0 < 128; k0 += 32) {
    bf16x8 a = *(const bf16x8*)&hb[r*136 + k0 + quad*8];
    #pragma unroll
    for (int tt = 0; tt < 4; tt++) {
      bf16x8 b = *(const bf16x8*)(wn2t + (size_t)(tt*16 + r)*128 + k0 + quad*8);
      acc2[tt] = __builtin_amdgcn_mfma_f32_16x16x32_bf16(a, b, acc2[tt], 0, 0, 0);
    }
  }
  __syncthreads();   // all hsm reads done before outs (aliased) is written

  #pragma unroll
  for (int tt = 0; tt < 4; tt++) {
    int col = tt*16 + r;
    float bias = bn2[col];
    #pragma unroll
    for (int i = 0; i < 4; i++)
      outs[(wave*16 + quad*4 + i)*64 + col] = acc2[tt][i] + bias;
  }
  __syncthreads();

  #pragma unroll
  for (int i = 0; i < 4; i++) {
    int idx = i*256 + t;
    int row = idx >> 4, c = idx & 15;
    int v2 = base + row;
    if (v2 < NN)
      *(float4*)(uh_n + (size_t)v2*64 + c*4) = *(const float4*)&outs[row*64 + c*4];
  }
}

// ---------------- launch ----------------
extern "C" void kernel_launch(void* const* d_in, const int* in_sizes, int n_in,
                              void* d_out, int out_size, void* d_ws, size_t ws_size,
                              hipStream_t stream)
{
  const float* nf  = (const float*)d_in[0];
  const float* ef  = (const float*)d_in[1];
  const int*   src = (const int*)d_in[2];
  const int*   dst = (const int*)d_in[3];
  const float* We1 = (const float*)d_in[4];
  const float* be1 = (const float*)d_in[5];
  const float* We2 = (const float*)d_in[6];
  const float* be2 = (const float*)d_in[7];
  const float* Wa1 = (const float*)d_in[8];
  const float* ba1 = (const float*)d_in[9];
  const float* Wa2 = (const float*)d_in[10];
  const float* ba2 = (const float*)d_in[11];
  const float* Wn1 = (const float*)d_in[12];
  const float* bn1 = (const float*)d_in[13];
  const float* Wn2 = (const float*)d_in[14];
  const float* bn2 = (const float*)d_in[15];

  // workspace layout (bytes), total 6,951,552 B (~6.6 MiB)
  char* ws = (char*)d_ws;
  u16*   w1t    = (u16*)  (ws + 0);         //  81920 B
  u16*   w2t    = (u16*)  (ws + 81920);     //  20480 B
  u16*   wn1t   = (u16*)  (ws + 102400);    //  32768 B
  u16*   wn2t   = (u16*)  (ws + 135168);    //  16384 B
  float* exu    = (float*)(ws + 151552);    //  NE*4 (unnormalized exp(logit))
  int*   head   = (int*)  (ws + 3551552);   //  NN*4
  int*   nxt    = (int*)  (ws + 3751552);   //  NE*4  -> end 6,951,552

  float* uh_n = (float*)d_out;                     // [NN, 64] f32
  float* uh_e = (float*)d_out + (size_t)NN * 64;   // [NE, 64] f32
  // nfb (bf16 nf, 6.4 MB) lives in the uh_n region: consumed only by edge_kernel,
  // which completes before agg_kernel overwrites the region with aggf.
  u16*   nfb  = (u16*)d_out;
  float* aggf = uh_n;

  prep_kernel<<<492, 256, 0, stream>>>(We1, Wa1, We2, Wa2, Wn1, Wn2,
                                       w1t, w2t, wn1t, wn2t, head);
  nfbf_kernel<<<3125, 256, 0, stream>>>(nf, nfb);
  link_kernel<<<(NE + 255)/256, 256, 0, stream>>>(dst, head, nxt);
  edge_kernel<<<NE/64, 256, 0, stream>>>(nfb, ef, src, dst, w1t, w2t,
                                         be1, ba1, be2, ba2, uh_e, exu);
  agg_kernel<<<(NN*64)/256, 256, 0, stream>>>(head, nxt, exu, uh_e, aggf);
  node_kernel<<<(NN + 63)/64, 256, 0, stream>>>(aggf, nf, wn1t, wn2t, bn1, bn2, uh_n);
}